// Round 4
// baseline (437.244 us; speedup 1.0000x reference)
//
#include <hip/hip_runtime.h>
#include <hip/hip_bf16.h>
#include <stdint.h>

#define N 8192
#define FIN 256
#define FOUT 64
#define WPB 8                    // waves per block = j-slices per 16-row group
#define JLEN (N / WPB)           // 1024 columns per wave
#define NITER (JLEN / 64)        // 16 chunks of 64 columns

typedef __attribute__((ext_vector_type(8))) short s8v;
typedef __attribute__((ext_vector_type(4))) float f4v;

// float -> bf16 bits, round-to-nearest-even (scalar fallback path)
__device__ __forceinline__ uint32_t f2bf(float f) {
  uint32_t u = __float_as_uint(f);
  return (u + 0x7FFFu + ((u >> 16) & 1u)) >> 16;
}

// pack two fp32 -> packed bf16 pair (v_cvt_pk_bf16_f32, RTNE)
__device__ __forceinline__ uint32_t pk2(float x, float y) {
  __hip_bfloat162 p = __float22bfloat162_rn(make_float2(x, y));
  union { __hip_bfloat162 b; uint32_t u; } c;
  c.b = p;
  return c.u;
}

// Kernel A: Wh = h@W (fp32 in regs), f1 = Wh@a1, f2 = Wh@a2, store WhT bf16 [64][8192]
__global__ __launch_bounds__(256) void gat_prep(
    const float* __restrict__ h, const float* __restrict__ W,
    const float* __restrict__ a,
    float* __restrict__ f1, float* __restrict__ f2,
    uint16_t* __restrict__ whT)
{
  const int c = threadIdx.x & 63;            // output feature
  const int wave = threadIdx.x >> 6;
  const int i0 = blockIdx.x * 16 + wave * 4; // 4 rows per wave
  float acc[4] = {0.f, 0.f, 0.f, 0.f};
  #pragma unroll 8
  for (int k = 0; k < FIN; ++k) {
    float wv = W[k * FOUT + c];              // coalesced across lanes
    #pragma unroll
    for (int r = 0; r < 4; ++r)              // h index wave-uniform -> s_load
      acc[r] += h[(size_t)(i0 + r) * FIN + k] * wv;
  }
  // lane c holds Wh[i0+r][c] == WhT[c][i0+r]: pack 4 bf16, one 8B store
  int2 pk;
  pk.x = (int)pk2(acc[0], acc[1]);
  pk.y = (int)pk2(acc[2], acc[3]);
  *(int2*)(whT + (size_t)c * N + i0) = pk;

  const float a1 = a[c], a2 = a[FOUT + c];
  #pragma unroll
  for (int r = 0; r < 4; ++r) {
    float v1 = acc[r] * a1;
    float v2 = acc[r] * a2;
    #pragma unroll
    for (int m = 32; m > 0; m >>= 1) {
      v1 += __shfl_xor(v1, m, 64);
      v2 += __shfl_xor(v2, m, 64);
    }
    if (c == 0) { f1[i0 + r] = v1; f2[i0 + r] = v2; }
  }
}

// Build one MFMA A-fragment (8 bf16 attention weights) from pre-loaded regs.
__device__ __forceinline__ s8v make_afrag_r(float f1v, int4 c0, int4 c1,
                                            float4 g0, float4 g1) {
  float e0 = f1v + g0.x; e0 = fmaxf(e0, 0.2f * e0); float w0 = (c0.x > 0) ? __expf(e0) : 0.f;
  float e1 = f1v + g0.y; e1 = fmaxf(e1, 0.2f * e1); float w1 = (c0.y > 0) ? __expf(e1) : 0.f;
  float e2 = f1v + g0.z; e2 = fmaxf(e2, 0.2f * e2); float w2 = (c0.z > 0) ? __expf(e2) : 0.f;
  float e3 = f1v + g0.w; e3 = fmaxf(e3, 0.2f * e3); float w3 = (c0.w > 0) ? __expf(e3) : 0.f;
  float e4 = f1v + g1.x; e4 = fmaxf(e4, 0.2f * e4); float w4 = (c1.x > 0) ? __expf(e4) : 0.f;
  float e5 = f1v + g1.y; e5 = fmaxf(e5, 0.2f * e5); float w5 = (c1.y > 0) ? __expf(e5) : 0.f;
  float e6 = f1v + g1.z; e6 = fmaxf(e6, 0.2f * e6); float w6 = (c1.z > 0) ? __expf(e6) : 0.f;
  float e7 = f1v + g1.w; e7 = fmaxf(e7, 0.2f * e7); float w7 = (c1.w > 0) ? __expf(e7) : 0.f;
  union { s8v v; uint32_t u[4]; } r;
  r.u[0] = pk2(w0, w1);
  r.u[1] = pk2(w2, w3);
  r.u[2] = pk2(w4, w5);
  r.u[3] = pk2(w6, w7);
  return r.v;
}

// Kernel B: fused flash GAT. Block = 8 waves x 16-row group; wave w owns
// j-slice [w*1024, (w+1)*1024). Denominator computed on the MFMA pipe via a
// ones-B fragment (consistent bf16 rounding with the numerator). One LDS
// reduction at the end, then divide + ELU + store — no partials, no 3rd kernel.
__global__ __launch_bounds__(512) void gat_fused(
    const int* __restrict__ adj, const float* __restrict__ f1,
    const float* __restrict__ f2, const uint16_t* __restrict__ whT,
    float* __restrict__ out)
{
  __shared__ float red[WPB][16][64];   // 32 KB numerator slabs
  __shared__ float redd[WPB][16];      // denominator slabs

  const int t = threadIdx.x;
  const int wave = t >> 6;
  const int lane = t & 63;
  const int i0 = blockIdx.x * 16;
  const int jb = wave * JLEN;
  const int m  = lane & 15;                 // A row / B col
  const int kg = lane >> 4;                 // k-group (8 elems each)

  const float f1v = f1[i0 + m];
  const int*      ap  = adj + (size_t)(i0 + m) * N + jb + kg * 8;
  const float*    fp  = f2 + jb + kg * 8;
  const uint16_t* bp0 = whT + (size_t)m * N + jb + kg * 8;

  f4v acc0 = {0.f, 0.f, 0.f, 0.f};
  f4v acc1 = acc0, acc2 = acc0, acc3 = acc0, accd = acc0;
  union { s8v v; uint32_t u[4]; } ones;
  ones.u[0] = 0x3F803F80u; ones.u[1] = 0x3F803F80u;
  ones.u[2] = 0x3F803F80u; ones.u[3] = 0x3F803F80u;

  // prefetch chunk 0: adj + f2 for both afrags
  int4   pc0 = *(const int4*)(ap);
  int4   pc1 = *(const int4*)(ap + 4);
  int4   pc2 = *(const int4*)(ap + 32);
  int4   pc3 = *(const int4*)(ap + 36);
  float4 pg0 = *(const float4*)(fp);
  float4 pg1 = *(const float4*)(fp + 4);
  float4 pg2 = *(const float4*)(fp + 32);
  float4 pg3 = *(const float4*)(fp + 36);

  #pragma unroll 1
  for (int jc = 0; jc < NITER; ++jc) {
    const int j0 = jc * 64;
    int4 c0 = pc0, c1 = pc1, c2 = pc2, c3 = pc3;
    float4 g0 = pg0, g1 = pg1, g2 = pg2, g3 = pg3;
    // issue next chunk's HBM loads before consuming current
    if (jc + 1 < NITER) {
      const int jn = j0 + 64;
      pc0 = *(const int4*)(ap + jn);
      pc1 = *(const int4*)(ap + jn + 4);
      pc2 = *(const int4*)(ap + jn + 32);
      pc3 = *(const int4*)(ap + jn + 36);
      pg0 = *(const float4*)(fp + jn);
      pg1 = *(const float4*)(fp + jn + 4);
      pg2 = *(const float4*)(fp + jn + 32);
      pg3 = *(const float4*)(fp + jn + 36);
    }
    s8v a0 = make_afrag_r(f1v, c0, c1, g0, g1);
    s8v a1 = make_afrag_r(f1v, c2, c3, g2, g3);
    const uint16_t* bp = bp0 + j0;
    s8v b00 = *(const s8v*)(bp);
    s8v b01 = *(const s8v*)(bp + 32);
    s8v b10 = *(const s8v*)(bp + 16 * N);
    s8v b11 = *(const s8v*)(bp + 16 * N + 32);
    s8v b20 = *(const s8v*)(bp + 32 * N);
    s8v b21 = *(const s8v*)(bp + 32 * N + 32);
    s8v b30 = *(const s8v*)(bp + 48 * N);
    s8v b31 = *(const s8v*)(bp + 48 * N + 32);
    acc0 = __builtin_amdgcn_mfma_f32_16x16x32_bf16(a0, b00, acc0, 0, 0, 0);
    acc0 = __builtin_amdgcn_mfma_f32_16x16x32_bf16(a1, b01, acc0, 0, 0, 0);
    acc1 = __builtin_amdgcn_mfma_f32_16x16x32_bf16(a0, b10, acc1, 0, 0, 0);
    acc1 = __builtin_amdgcn_mfma_f32_16x16x32_bf16(a1, b11, acc1, 0, 0, 0);
    acc2 = __builtin_amdgcn_mfma_f32_16x16x32_bf16(a0, b20, acc2, 0, 0, 0);
    acc2 = __builtin_amdgcn_mfma_f32_16x16x32_bf16(a1, b21, acc2, 0, 0, 0);
    acc3 = __builtin_amdgcn_mfma_f32_16x16x32_bf16(a0, b30, acc3, 0, 0, 0);
    acc3 = __builtin_amdgcn_mfma_f32_16x16x32_bf16(a1, b31, acc3, 0, 0, 0);
    // denominator: row sums of the same bf16 weights, on the MFMA pipe
    accd = __builtin_amdgcn_mfma_f32_16x16x32_bf16(a0, ones.v, accd, 0, 0, 0);
    accd = __builtin_amdgcn_mfma_f32_16x16x32_bf16(a1, ones.v, accd, 0, 0, 0);
  }

  // write this wave's partial tile; C/D layout: col = lane&15, row = kg*4 + reg
  #pragma unroll
  for (int r = 0; r < 4; ++r) {
    int row = kg * 4 + r;
    red[wave][row][     m] = acc0[r];
    red[wave][row][16 + m] = acc1[r];
    red[wave][row][32 + m] = acc2[r];
    red[wave][row][48 + m] = acc3[r];
  }
  if (m == 0) {
    #pragma unroll
    for (int r = 0; r < 4; ++r) redd[wave][kg * 4 + r] = accd[r];
  }
  __syncthreads();

  // 512 threads reduce 1024 outputs (2 each): stride-1 cols -> conflict-free
  #pragma unroll
  for (int idx = t; idx < 16 * 64; idx += 512) {
    const int row = idx >> 6;
    const int col = idx & 63;
    float num = 0.f, den = 0.f;
    #pragma unroll
    for (int w = 0; w < WPB; ++w) {
      num += red[w][row][col];
      den += redd[w][row];
    }
    float hp = num / den;
    out[(size_t)(i0 + row) * FOUT + col] = (hp > 0.f) ? hp : (__expf(hp) - 1.f);
  }
}

extern "C" void kernel_launch(void* const* d_in, const int* in_sizes, int n_in,
                              void* d_out, int out_size, void* d_ws, size_t ws_size,
                              hipStream_t stream) {
  const float* h   = (const float*)d_in[0];
  const int*   adj = (const int*)d_in[1];
  const float* W   = (const float*)d_in[2];
  const float* a   = (const float*)d_in[3];
  float* out = (float*)d_out;

  float* f1 = (float*)d_ws;                     // 8192 f32
  float* f2 = f1 + N;                           // 8192 f32
  uint16_t* whT = (uint16_t*)(f2 + N);          // 64*8192 bf16 = 1 MB

  gat_prep<<<N / 16, 256, 0, stream>>>(h, W, a, f1, f2, whT);
  gat_fused<<<N / 16, 512, 0, stream>>>(adj, f1, f2, whT, out);
}

// Round 5
// 436.234 us; speedup vs baseline: 1.0023x; 1.0023x over previous
//
#include <hip/hip_runtime.h>
#include <hip/hip_bf16.h>
#include <stdint.h>

#define N 8192
#define FIN 256
#define FOUT 64
#define QSPLIT 8                 // j-dimension split per 16-row group
#define NTASK (512 * QSPLIT)     // 4096 wave-tasks
#define JLEN (N / QSPLIT)        // 1024 columns per task
#define NITER (JLEN / 64)        // 16 chunks of 64 columns

typedef __attribute__((ext_vector_type(8))) short s8v;
typedef __attribute__((ext_vector_type(4))) float f4v;

// pack two fp32 -> packed bf16 pair (v_cvt_pk_bf16_f32, RTNE)
__device__ __forceinline__ uint32_t pk2(float x, float y) {
  __hip_bfloat162 p = __float22bfloat162_rn(make_float2(x, y));
  union { __hip_bfloat162 b; uint32_t u; } c;
  c.b = p;
  return c.u;
}

// Kernel A: Wh = h@W (fp32 in regs), f1 = Wh@a1, f2 = Wh@a2, store WhT bf16 [64][8192]
// 4 rows per wave, 4 waves per block -> 512 blocks, 8 waves/CU.
__global__ __launch_bounds__(256) void gat_prep(
    const float* __restrict__ h, const float* __restrict__ W,
    const float* __restrict__ a,
    float* __restrict__ f1, float* __restrict__ f2,
    uint16_t* __restrict__ whT)
{
  const int c = threadIdx.x & 63;            // output feature
  const int wave = threadIdx.x >> 6;
  const int i0 = blockIdx.x * 16 + wave * 4; // 4 rows per wave
  float acc[4] = {0.f, 0.f, 0.f, 0.f};
  #pragma unroll 8
  for (int k = 0; k < FIN; ++k) {
    float wv = W[k * FOUT + c];              // coalesced across lanes
    #pragma unroll
    for (int r = 0; r < 4; ++r)              // h index wave-uniform -> s_load
      acc[r] += h[(size_t)(i0 + r) * FIN + k] * wv;
  }
  // lane c holds Wh[i0+r][c] == WhT[c][i0+r]: pack 4 bf16, one 8B store
  int2 pk;
  pk.x = (int)pk2(acc[0], acc[1]);
  pk.y = (int)pk2(acc[2], acc[3]);
  *(int2*)(whT + (size_t)c * N + i0) = pk;

  const float a1 = a[c], a2 = a[FOUT + c];
  #pragma unroll
  for (int r = 0; r < 4; ++r) {
    float v1 = acc[r] * a1;
    float v2 = acc[r] * a2;
    #pragma unroll
    for (int m = 32; m > 0; m >>= 1) {
      v1 += __shfl_xor(v1, m, 64);
      v2 += __shfl_xor(v2, m, 64);
    }
    if (c == 0) { f1[i0 + r] = v1; f2[i0 + r] = v2; }
  }
}

// Build one MFMA A-fragment (8 bf16 attention weights) from pre-loaded regs.
__device__ __forceinline__ s8v make_afrag_r(float f1v, int4 c0, int4 c1,
                                            float4 g0, float4 g1) {
  float e0 = f1v + g0.x; e0 = fmaxf(e0, 0.2f * e0); float w0 = (c0.x > 0) ? __expf(e0) : 0.f;
  float e1 = f1v + g0.y; e1 = fmaxf(e1, 0.2f * e1); float w1 = (c0.y > 0) ? __expf(e1) : 0.f;
  float e2 = f1v + g0.z; e2 = fmaxf(e2, 0.2f * e2); float w2 = (c0.z > 0) ? __expf(e2) : 0.f;
  float e3 = f1v + g0.w; e3 = fmaxf(e3, 0.2f * e3); float w3 = (c0.w > 0) ? __expf(e3) : 0.f;
  float e4 = f1v + g1.x; e4 = fmaxf(e4, 0.2f * e4); float w4 = (c1.x > 0) ? __expf(e4) : 0.f;
  float e5 = f1v + g1.y; e5 = fmaxf(e5, 0.2f * e5); float w5 = (c1.y > 0) ? __expf(e5) : 0.f;
  float e6 = f1v + g1.z; e6 = fmaxf(e6, 0.2f * e6); float w6 = (c1.z > 0) ? __expf(e6) : 0.f;
  float e7 = f1v + g1.w; e7 = fmaxf(e7, 0.2f * e7); float w7 = (c1.w > 0) ? __expf(e7) : 0.f;
  union { s8v v; uint32_t u[4]; } r;
  r.u[0] = pk2(w0, w1);
  r.u[1] = pk2(w2, w3);
  r.u[2] = pk2(w4, w5);
  r.u[3] = pk2(w6, w7);
  return r.v;
}

// Kernel B: barrier-free flash GAT (R3 structure). One wave = 16 rows x 1024
// cols partial. Depth-1 register prefetch of adj/f2; whT L1/L2-hot.
// Denominator on the MFMA pipe via ones-B fragment (consistent rounding).
__global__ __launch_bounds__(256) void gat_main2(
    const int* __restrict__ adj, const float* __restrict__ f1,
    const float* __restrict__ f2, const uint16_t* __restrict__ whT,
    float* __restrict__ pnum, float* __restrict__ pden)
{
  const int t = threadIdx.x;
  const int wave = t >> 6;
  const int lane = t & 63;
  const int task = blockIdx.x * 4 + wave;   // 0..NTASK-1
  const int group = task / QSPLIT;          // 16-row group
  const int quarter = task % QSPLIT;        // j-slice
  const int i0 = group * 16;
  const int jb = quarter * JLEN;
  const int m  = lane & 15;                 // A row / B col
  const int kg = lane >> 4;                 // k-group (8 elems each)

  const float f1v = f1[i0 + m];
  const int*      ap  = adj + (size_t)(i0 + m) * N + jb + kg * 8;
  const float*    fp  = f2 + jb + kg * 8;
  const uint16_t* bp0 = whT + (size_t)m * N + jb + kg * 8;

  f4v acc0 = {0.f, 0.f, 0.f, 0.f};
  f4v acc1 = acc0, acc2 = acc0, acc3 = acc0, accd = acc0;
  union { s8v v; uint32_t u[4]; } ones;
  ones.u[0] = 0x3F803F80u; ones.u[1] = 0x3F803F80u;
  ones.u[2] = 0x3F803F80u; ones.u[3] = 0x3F803F80u;

  // prefetch chunk 0: adj + f2 for both afrags
  int4   pc0 = *(const int4*)(ap);
  int4   pc1 = *(const int4*)(ap + 4);
  int4   pc2 = *(const int4*)(ap + 32);
  int4   pc3 = *(const int4*)(ap + 36);
  float4 pg0 = *(const float4*)(fp);
  float4 pg1 = *(const float4*)(fp + 4);
  float4 pg2 = *(const float4*)(fp + 32);
  float4 pg3 = *(const float4*)(fp + 36);

  #pragma unroll 1
  for (int jc = 0; jc < NITER; ++jc) {
    const int j0 = jc * 64;
    int4 c0 = pc0, c1 = pc1, c2 = pc2, c3 = pc3;
    float4 g0 = pg0, g1 = pg1, g2 = pg2, g3 = pg3;
    // issue next chunk's HBM loads before consuming current
    if (jc + 1 < NITER) {
      const int jn = j0 + 64;
      pc0 = *(const int4*)(ap + jn);
      pc1 = *(const int4*)(ap + jn + 4);
      pc2 = *(const int4*)(ap + jn + 32);
      pc3 = *(const int4*)(ap + jn + 36);
      pg0 = *(const float4*)(fp + jn);
      pg1 = *(const float4*)(fp + jn + 4);
      pg2 = *(const float4*)(fp + jn + 32);
      pg3 = *(const float4*)(fp + jn + 36);
    }
    s8v a0 = make_afrag_r(f1v, c0, c1, g0, g1);
    s8v a1 = make_afrag_r(f1v, c2, c3, g2, g3);
    const uint16_t* bp = bp0 + j0;
    s8v b00 = *(const s8v*)(bp);
    s8v b01 = *(const s8v*)(bp + 32);
    s8v b10 = *(const s8v*)(bp + 16 * N);
    s8v b11 = *(const s8v*)(bp + 16 * N + 32);
    s8v b20 = *(const s8v*)(bp + 32 * N);
    s8v b21 = *(const s8v*)(bp + 32 * N + 32);
    s8v b30 = *(const s8v*)(bp + 48 * N);
    s8v b31 = *(const s8v*)(bp + 48 * N + 32);
    acc0 = __builtin_amdgcn_mfma_f32_16x16x32_bf16(a0, b00, acc0, 0, 0, 0);
    acc0 = __builtin_amdgcn_mfma_f32_16x16x32_bf16(a1, b01, acc0, 0, 0, 0);
    acc1 = __builtin_amdgcn_mfma_f32_16x16x32_bf16(a0, b10, acc1, 0, 0, 0);
    acc1 = __builtin_amdgcn_mfma_f32_16x16x32_bf16(a1, b11, acc1, 0, 0, 0);
    acc2 = __builtin_amdgcn_mfma_f32_16x16x32_bf16(a0, b20, acc2, 0, 0, 0);
    acc2 = __builtin_amdgcn_mfma_f32_16x16x32_bf16(a1, b21, acc2, 0, 0, 0);
    acc3 = __builtin_amdgcn_mfma_f32_16x16x32_bf16(a0, b30, acc3, 0, 0, 0);
    acc3 = __builtin_amdgcn_mfma_f32_16x16x32_bf16(a1, b31, acc3, 0, 0, 0);
    // denominator: row sums of the same bf16 weights, on the MFMA pipe
    accd = __builtin_amdgcn_mfma_f32_16x16x32_bf16(a0, ones.v, accd, 0, 0, 0);
    accd = __builtin_amdgcn_mfma_f32_16x16x32_bf16(a1, ones.v, accd, 0, 0, 0);
  }

  // store fp32 partials; C/D layout: col = lane&15, row = kg*4 + reg
  float* np = pnum + (size_t)task * (16 * 64);
  #pragma unroll
  for (int r = 0; r < 4; ++r) {
    int row = kg * 4 + r;
    np[row * 64 +      m] = acc0[r];
    np[row * 64 + 16 + m] = acc1[r];
    np[row * 64 + 32 + m] = acc2[r];
    np[row * 64 + 48 + m] = acc3[r];
  }
  // accd[r] = den(row kg*4+r), identical across cols; 4 lanes (m==0) cover 16 rows
  if (m == 0) {
    #pragma unroll
    for (int r = 0; r < 4; ++r) pden[task * 16 + kg * 4 + r] = accd[r];
  }
}

// Kernel C: combine QSPLIT j-slice partials, divide, ELU.
__global__ __launch_bounds__(256) void gat_combine(
    const float* __restrict__ pnum, const float* __restrict__ pden,
    float* __restrict__ out)
{
  const int idx = blockIdx.x * 256 + threadIdx.x;  // 0 .. 8192*64-1
  const int i = idx >> 6;
  const int c = idx & 63;
  const int g = i >> 4;
  const int r = i & 15;
  const size_t base = (size_t)g * QSPLIT * 1024 + (size_t)r * 64 + c;
  float num = 0.f;
  #pragma unroll
  for (int q = 0; q < QSPLIT; ++q) num += pnum[base + (size_t)q * 1024];
  const int db = g * (QSPLIT * 16) + r;
  float den = 0.f;
  #pragma unroll
  for (int q = 0; q < QSPLIT; ++q) den += pden[db + q * 16];
  float hp = num / den;
  out[idx] = (hp > 0.f) ? hp : (__expf(hp) - 1.f);
}

extern "C" void kernel_launch(void* const* d_in, const int* in_sizes, int n_in,
                              void* d_out, int out_size, void* d_ws, size_t ws_size,
                              hipStream_t stream) {
  const float* h   = (const float*)d_in[0];
  const int*   adj = (const int*)d_in[1];
  const float* W   = (const float*)d_in[2];
  const float* a   = (const float*)d_in[3];
  float* out = (float*)d_out;

  float* f1 = (float*)d_ws;                     // 8192 f32
  float* f2 = f1 + N;                           // 8192 f32
  uint16_t* whT = (uint16_t*)(f2 + N);          // 64*8192 bf16 = 1 MB
  float* pnum = (float*)(whT + (size_t)FOUT * N);   // NTASK*16*64 f32 = 16 MB
  float* pden = pnum + (size_t)NTASK * 16 * 64;     // NTASK*16 f32

  gat_prep<<<N / 16, 256, 0, stream>>>(h, W, a, f1, f2, whT);
  gat_main2<<<NTASK / 4, 256, 0, stream>>>(adj, f1, f2, whT, pnum, pden);
  gat_combine<<<(N * FOUT) / 256, 256, 0, stream>>>(pnum, pden, out);
}